// Round 4
// baseline (224.383 us; speedup 1.0000x reference)
//
#include <hip/hip_runtime.h>
#include <math.h>

#define NHALF 4096
#define NTOT  8192
#define DIN   512
#define DF    64      // Fea row pitch (50 real + 14 zeros)
#define DFR   50      // real deep-feature dim
#define BM    128     // tile M = N
#define FPITCH 132    // f32 pitch of staged Ft tiles
#define KHALF 25      // Dd k staged in two halves
#define NBI   64      // 8192/128
#define NTRI  2080    // 64*65/2 upper-tri blocks

typedef short short8 __attribute__((ext_vector_type(8)));
typedef float f32x4 __attribute__((ext_vector_type(4)));

__device__ __forceinline__ float softplus_f(float x) {
    return fmaxf(x, 0.f) + log1pf(expf(-fabsf(x)));
}

__device__ __forceinline__ unsigned cvt_pk_bf16(float lo, float hi) {
    unsigned r;
    asm("v_cvt_pk_bf16_f32 %0, %1, %2" : "=v"(r) : "v"(lo), "v"(hi));
    return r;
}

__device__ __forceinline__ void gload_lds16(const void* g, void* l) {
    __builtin_amdgcn_global_load_lds(
        (const __attribute__((address_space(1))) void*)g,
        (__attribute__((address_space(3))) void*)l, 16, 0, 0);
}

// ---------------- Kernel A: featurize + norms + bf16 convert ----------------
__global__ __launch_bounds__(256) void featurize_kernel(
    const float* __restrict__ Xs, const float* __restrict__ Xt,
    const float* __restrict__ W1, const float* __restrict__ b1,
    const float* __restrict__ W2, const float* __restrict__ b2,
    const float* __restrict__ W3, const float* __restrict__ b3,
    const float* __restrict__ W4, const float* __restrict__ b4,
    float* __restrict__ Fea, float* __restrict__ norm_org, float* __restrict__ norm_fea,
    unsigned short* __restrict__ Xbf)
{
    int row  = (blockIdx.x * blockDim.x + threadIdx.x) >> 6;
    int lane = threadIdx.x & 63;
    if (row >= NTOT) return;
    const float* src = (row < NHALF) ? (Xs + (size_t)row * DIN)
                                     : (Xt + (size_t)(row - NHALF) * DIN);
    float4 v0 = ((const float4*)src)[lane * 2];
    float4 v1 = ((const float4*)src)[lane * 2 + 1];
    float x[8] = {v0.x, v0.y, v0.z, v0.w, v1.x, v1.y, v1.z, v1.w};

    // bf16 copy (concatenated layout)
    unsigned q0 = cvt_pk_bf16(x[0], x[1]);
    unsigned q1 = cvt_pk_bf16(x[2], x[3]);
    unsigned q2 = cvt_pk_bf16(x[4], x[5]);
    unsigned q3 = cvt_pk_bf16(x[6], x[7]);
    *(uint4*)(Xbf + (size_t)row * DIN + lane * 8) = make_uint4(q0, q1, q2, q3);

    float p[10];
#pragma unroll
    for (int j = 0; j < 10; ++j) p[j] = 0.f;
    float on = 0.f;
    int ibase = lane * 8;
#pragma unroll
    for (int t = 0; t < 8; ++t) {
        float xv = x[t];
        on += xv * xv;
        const float* wrow = W1 + (size_t)(ibase + t) * 10;
#pragma unroll
        for (int j = 0; j < 10; ++j) p[j] = fmaf(xv, wrow[j], p[j]);
    }
#pragma unroll
    for (int m = 32; m >= 1; m >>= 1) {
#pragma unroll
        for (int j = 0; j < 10; ++j) p[j] += __shfl_xor(p[j], m, 64);
        on += __shfl_xor(on, m, 64);
    }
    float h[10], h2[10];
#pragma unroll
    for (int j = 0; j < 10; ++j) h[j] = softplus_f(p[j] + b1[j]);
#pragma unroll
    for (int j = 0; j < 10; ++j) {
        float a = b2[j];
#pragma unroll
        for (int k = 0; k < 10; ++k) a = fmaf(h[k], W2[k * 10 + j], a);
        h2[j] = softplus_f(a);
    }
#pragma unroll
    for (int j = 0; j < 10; ++j) {
        float a = b3[j];
#pragma unroll
        for (int k = 0; k < 10; ++k) a = fmaf(h2[k], W3[k * 10 + j], a);
        h[j] = softplus_f(a);
    }
    float o = 0.f;
    if (lane < DFR) {
        float a = b4[lane];
#pragma unroll
        for (int k = 0; k < 10; ++k) a = fmaf(h[k], W4[k * 50 + lane], a);
        o = a;
    }
    Fea[(size_t)row * DF + lane] = o;
    float fn = o * o;
#pragma unroll
    for (int m = 32; m >= 1; m >>= 1) fn += __shfl_xor(fn, m, 64);
    if (lane == 0) { norm_org[row] = on; norm_fea[row] = fn; }
}

// ---------------- Kernel C: fused MFMA(Do) + fp32(Dd) pairwise, upper-tri ----------------
// 512 threads / 8 waves, wave tile 32x64. LDS: 2 x (A 8KB + B 8KB) = 32 KB.
// Cross-diagonal (j == i + 4096) entries are zeroed: they cancel exactly against
// the reference's +2*tr(Kxy) term, so no separate trace kernel is needed.
__global__ __launch_bounds__(512, 4) void pairwise_kernel(
    const unsigned short* __restrict__ Xbf,
    const float* __restrict__ Fea,
    const float* __restrict__ norm_org, const float* __restrict__ norm_fea,
    const float* __restrict__ epsP, const float* __restrict__ sigP,
    const float* __restrict__ sig0P,
    double* __restrict__ partialsC)
{
    __shared__ char smem[32768] __attribute__((aligned(128)));
    __shared__ double sredC[8];

    int bid = blockIdx.x;
    // triangular decode: bi <= bj
    int bi = (int)((129.0 - sqrt(16641.0 - 8.0 * (double)bid)) * 0.5);
    while (NBI * (bi + 1) - (bi + 1) * bi / 2 <= bid) ++bi;
    while (NBI * bi - bi * (bi - 1) / 2 > bid) --bi;
    int bj = bi + (bid - (NBI * bi - bi * (bi - 1) / 2));

    int tid = threadIdx.x;
    int lane = tid & 63, wave = tid >> 6;     // 8 waves
    int g = lane >> 4, l15 = lane & 15;
    int i0w = (wave >> 1) * 32;               // 4 row-groups of 32
    int j0w = (wave & 1) * 64;                // 2 col-groups of 64
    int ri = bi * BM, rj = bj * BM;

    // staging source (thread t -> row t>>2, inverse-swizzled 16B chunk)
    int srow = tid >> 2;
    int schunk = (tid & 3) ^ ((srow >> 1) & 3);
    const char* sA0 = (const char*)(Xbf + (size_t)(ri + srow) * DIN + schunk * 8);
    const char* sB0 = (const char*)(Xbf + (size_t)(rj + srow) * DIN + schunk * 8);
    char* lbase = (char*)smem + wave * 1024;  // wave-uniform LDS dest

    // fragment read offsets (swizzled): row pitch 32 shorts, chunk 8 shorts
    int swz = (l15 >> 1) & 3;
    int offA = (i0w + l15) * 32 + (g ^ swz) * 8;
    int offB = (j0w + l15) * 32 + (g ^ swz) * 8;

    f32x4 acc[2][4];
#pragma unroll
    for (int a = 0; a < 2; ++a)
#pragma unroll
        for (int b = 0; b < 4; ++b) acc[a][b] = (f32x4){0.f, 0.f, 0.f, 0.f};

    // ---- Phase 1: Do via bf16 MFMA over K=512, double-buffered gload_lds ----
    gload_lds16(sA0, lbase);
    gload_lds16(sB0, lbase + 8192);
    __syncthreads();

    for (int kk = 0; kk < 16; ++kk) {
        int cur = kk & 1;
        if (kk < 15) {
            char* ld = lbase + (cur ^ 1) * 16384;
            gload_lds16(sA0 + (kk + 1) * 64, ld);
            gload_lds16(sB0 + (kk + 1) * 64, ld + 8192);
        }
        const unsigned short* tc = (const unsigned short*)(smem + cur * 16384);
        short8 af[2], bfr[4];
#pragma unroll
        for (int a = 0; a < 2; ++a)
            af[a] = *(const short8*)(tc + offA + a * 512);
#pragma unroll
        for (int b = 0; b < 4; ++b)
            bfr[b] = *(const short8*)(tc + 4096 + offB + b * 512);
#pragma unroll
        for (int a = 0; a < 2; ++a)
#pragma unroll
            for (int b = 0; b < 4; ++b)
                acc[a][b] = __builtin_amdgcn_mfma_f32_16x16x32_bf16(af[a], bfr[b], acc[a][b], 0, 0, 0);
        __syncthreads();
    }

    // ---- Phase 2: Dd in fp32, aligned to MFMA C layout ----
    // lane owns i = i0w+16a+4g+r (a in 0..1, r in 0..3), j = j0w+16b+l15 (b in 0..3)
    float* FtA = (float*)smem;
    float* FtB = (float*)(smem + 13216);
    float dd[8][4];
#pragma unroll
    for (int q = 0; q < 8; ++q)
#pragma unroll
        for (int b = 0; b < 4; ++b) dd[q][b] = 0.f;

    for (int h = 0; h < 2; ++h) {
        {   // stage transposed feature half-tiles Ft[k][row]
            int r = tid >> 2;
            int kpar = tid & 3;
            const float* fa = Fea + (size_t)(ri + r) * DF + h * KHALF;
            const float* fb = Fea + (size_t)(rj + r) * DF + h * KHALF;
#pragma unroll
            for (int m = 0; m < 7; ++m) {
                int kq = kpar + 4 * m;
                if (kq < KHALF) {
                    FtA[kq * FPITCH + r] = fa[kq];
                    FtB[kq * FPITCH + r] = fb[kq];
                }
            }
        }
        __syncthreads();
        for (int k = 0; k < KHALF; ++k) {
            f32x4 va[2];
            float vj[4];
#pragma unroll
            for (int a = 0; a < 2; ++a)
                va[a] = *(const f32x4*)(FtA + k * FPITCH + i0w + 16 * a + 4 * g);
#pragma unroll
            for (int b = 0; b < 4; ++b)
                vj[b] = FtB[k * FPITCH + j0w + 16 * b + l15];
#pragma unroll
            for (int a = 0; a < 2; ++a)
#pragma unroll
                for (int r = 0; r < 4; ++r) {
                    float fv = va[a][r];
#pragma unroll
                    for (int b = 0; b < 4; ++b)
                        dd[a * 4 + r][b] = fmaf(fv, vj[b], dd[a * 4 + r][b]);
                }
        }
        __syncthreads();
    }

    // ---- Epilogue ----
    float oni[8], fni[8], onj[4], fnj[4];
#pragma unroll
    for (int a = 0; a < 2; ++a)
#pragma unroll
        for (int r = 0; r < 4; ++r) {
            int i = ri + i0w + 16 * a + 4 * g + r;
            oni[a * 4 + r] = norm_org[i];
            fni[a * 4 + r] = norm_fea[i];
        }
#pragma unroll
    for (int b = 0; b < 4; ++b) {
        int j = rj + j0w + 16 * b + l15;
        onj[b] = norm_org[j];
        fnj[b] = norm_fea[j];
    }
    float ep = 1.f / (1.f + expf(-epsP[0]));
    float s = sigP[0], s0 = sig0P[0];
    float inv_s  = 1.f / (s * s);
    float inv_s0 = 1.f / (s0 * s0);
    float sgn = ((ri < NHALF) == (rj < NHALF)) ? 1.f : -1.f;
    bool diag = (bi == bj);
    bool killdiag = diag || (bj == bi + NHALF / BM);  // self-pairs or (p, p+4096) pairs
    float wsgn = sgn * (diag ? 1.f : 2.f);

    double loc = 0.0;
#pragma unroll
    for (int a = 0; a < 2; ++a)
#pragma unroll
        for (int b = 0; b < 4; ++b)
#pragma unroll
            for (int r = 0; r < 4; ++r) {
                float Do = fmaxf(oni[a * 4 + r] + onj[b] - 2.f * acc[a][b][r], 0.f);
                float Dd = fmaxf(fni[a * 4 + r] + fnj[b] - 2.f * dd[a * 4 + r][b], 0.f);
                float eo = __expf(-Do * inv_s);
                float K = (1.f - ep) * __expf(-Dd * inv_s0) * eo + ep * eo;
                if (killdiag && (i0w + 16 * a + 4 * g + r == j0w + 16 * b + l15)) K = 0.f;
                loc += (double)(wsgn * K);
            }
#pragma unroll
    for (int m = 32; m >= 1; m >>= 1) loc += __shfl_xor(loc, m, 64);
    if (lane == 0) sredC[wave] = loc;
    __syncthreads();
    if (tid == 0) {
        double S = 0.0;
#pragma unroll
        for (int w = 0; w < 8; ++w) S += sredC[w];
        partialsC[bid] = S;
    }
}

// ---------------- Kernel D: final reduce ----------------
__global__ __launch_bounds__(256) void reduce_kernel(
    const double* __restrict__ partialsC, float* __restrict__ out)
{
    double s = 0.0;
    for (int i = threadIdx.x; i < NTRI; i += 256) s += partialsC[i];
#pragma unroll
    for (int m = 32; m >= 1; m >>= 1) s += __shfl_xor(s, m, 64);
    __shared__ double ss[4];
    int w = threadIdx.x >> 6;
    if ((threadIdx.x & 63) == 0) ss[w] = s;
    __syncthreads();
    if (threadIdx.x == 0) {
        double S = ss[0] + ss[1] + ss[2] + ss[3];
        out[0] = (float)(S / (4096.0 * 4095.0));
    }
}

extern "C" void kernel_launch(void* const* d_in, const int* in_sizes, int n_in,
                              void* d_out, int out_size, void* d_ws, size_t ws_size,
                              hipStream_t stream)
{
    const float* Xs  = (const float*)d_in[0];
    const float* Xt  = (const float*)d_in[1];
    const float* W1  = (const float*)d_in[2];
    const float* b1  = (const float*)d_in[3];
    const float* W2  = (const float*)d_in[4];
    const float* b2  = (const float*)d_in[5];
    const float* W3  = (const float*)d_in[6];
    const float* b3  = (const float*)d_in[7];
    const float* W4  = (const float*)d_in[8];
    const float* b4  = (const float*)d_in[9];
    const float* epsP  = (const float*)d_in[10];
    const float* sigP  = (const float*)d_in[11];
    const float* sig0P = (const float*)d_in[12];
    float* out = (float*)d_out;

    char* ws = (char*)d_ws;
    unsigned short* Xbf = (unsigned short*)ws;                   // 8192*512 bf16 = 8 MB
    float* Fea      = (float*)(ws + (size_t)NTOT * DIN * 2);     // 8192*64 f32
    float* norm_org = Fea + (size_t)NTOT * DF;                   // 8192
    float* norm_fea = norm_org + NTOT;                           // 8192
    double* partialsC = (double*)(norm_fea + NTOT);              // 2080

    featurize_kernel<<<dim3(2048), dim3(256), 0, stream>>>(
        Xs, Xt, W1, b1, W2, b2, W3, b3, W4, b4, Fea, norm_org, norm_fea, Xbf);
    pairwise_kernel<<<dim3(NTRI), dim3(512), 0, stream>>>(
        Xbf, Fea, norm_org, norm_fea, epsP, sigP, sig0P, partialsC);
    reduce_kernel<<<dim3(1), dim3(256), 0, stream>>>(partialsC, out);
}